// Round 15
// baseline (182.203 us; speedup 1.0000x reference)
//
#include <hip/hip_runtime.h>
#include <hip/hip_fp16.h>
#include <math.h>

#define HP   2080          // padded height (2048 + 2*16)
#define WP   2080          // padded width
#define MARG 16
#define WOUT 2048
#define HOUT 2048
#define RAD  16            // truncation radius; tail mass ~2e-7 (threshold 9.9e-3)
#define TDIM 33            // 33x33 canvas tiles of 64x64
#define NT   (TDIM * TDIM) // 1089 buckets
#define CAP  1536          // bucket capacity; expected max ~1170
#define PST  65            // patch col stride (64 cols + 1 pad, odd -> conflict-free)
#define CSTR 16            // cursor line padding (kept from R14; harmless)
#define NBLK 256
#define SCAT_T 1024
#define SCAT_IT 4          // 256*1024*4 >= N

// exact discrete tap via Poisson summation: g[n] = sqrt(pi/200)*exp(-pi^2 n^2/200)
__device__ __forceinline__ void make_weights(float* wreg) {
#pragma unroll
    for (int t = 0; t <= RAD; ++t)
        wreg[t] = 0.12533141373155003f * __expf(-0.04934802200544679f * (float)(t * t));
}

// 33-tap conv over a 40-window: a[k] = sum_{j=k..k+32} base[j*stride] * g[|j-k-16|]
__device__ __forceinline__ void conv8(const float* __restrict__ base, int stride,
                                      const float* __restrict__ wreg, float* __restrict__ a) {
#pragma unroll
    for (int k = 0; k < 8; ++k) a[k] = 0.0f;
#pragma unroll
    for (int j = 0; j < 40; ++j) {
        float v = base[j * stride];
#pragma unroll
        for (int k = 0; k < 8; ++k)
            if (j >= k && j <= k + 32)
                a[k] += v * wreg[(j - k - 16 < 0) ? (k + 16 - j) : (j - k - 16)];
    }
}

// ---------------------------------------------------------------------------
// pass 1: scatter into canvas-tile buckets (1.03x dup: points with cell
// row%64==63 / col%64==63 duplicated into the tile below / right; lr1/lc1
// in [0,64] are cell coords +1 relative to the bucket's 64x64 block).
// FROZEN from R14.
// ---------------------------------------------------------------------------
__global__ __launch_bounds__(SCAT_T) void scatter_kernel(const float2* __restrict__ pos,
                                                         const float* __restrict__ inten,
                                                         int* __restrict__ cursor,  // [NT*CSTR], zeroed
                                                         ushort4* __restrict__ bins,
                                                         int n) {
    __shared__ int lhist[NT];
    __shared__ int lbase[NT];
    const int tid = threadIdx.x;
    for (int i = tid; i < NT; i += SCAT_T) lhist[i] = 0;
    __syncthreads();
    const int stride = NBLK * SCAT_T;
    const int start  = blockIdx.x * SCAT_T + tid;
    unsigned ra[SCAT_IT], rb[SCAT_IT], rc[SCAT_IT];
#pragma unroll
    for (int it = 0; it < SCAT_IT; ++it) {
        int i = start + it * stride;
        if (i < n) {
            float2 p = pos[i];
            float I  = inten[i];
            float px = p.x + MARG, py = p.y + MARG;
            int col = (int)floorf(px), row = (int)floorf(py);
            row = min(max(row, 0), HP - 1);
            col = min(max(col, 0), WP - 1);
            float dy = py - (float)row, dx = px - (float)col;
            ra[it] = ((unsigned)row << 12) | (unsigned)col;
            rb[it] = (unsigned)__half_as_ushort(__float2half(dx))
                   | ((unsigned)__half_as_ushort(__float2half(dy)) << 16);
            rc[it] = (unsigned)__half_as_ushort(__float2half(I));
            int tr = row >> 6, tc = col >> 6;
            int er = ((row & 63) == 63) ? 1 : 0;
            int ec = ((col & 63) == 63) ? 1 : 0;
            for (int dr = 0; dr <= er; ++dr)
                for (int dc = 0; dc <= ec; ++dc)
                    atomicAdd(&lhist[(tr + dr) * TDIM + tc + dc], 1);
        } else ra[it] = 0xffffffffu;
    }
    __syncthreads();
    for (int i = tid; i < NT; i += SCAT_T) {
        int c = lhist[i];
        lbase[i] = (c > 0) ? atomicAdd(&cursor[i * CSTR], c) : 0;
        lhist[i] = 0;
    }
    __syncthreads();
#pragma unroll
    for (int it = 0; it < SCAT_IT; ++it) {
        if (ra[it] != 0xffffffffu) {
            int row = (int)(ra[it] >> 12), col = (int)(ra[it] & 4095u);
            int tr = row >> 6, tc = col >> 6;
            int er = ((row & 63) == 63) ? 1 : 0;
            int ec = ((col & 63) == 63) ? 1 : 0;
            for (int dr = 0; dr <= er; ++dr)
                for (int dc = 0; dc <= ec; ++dc) {
                    int b   = (tr + dr) * TDIM + tc + dc;
                    int lr1 = row - ((tr + dr) << 6) + 1;   // 0..64
                    int lc1 = col - ((tc + dc) << 6) + 1;   // 0..64
                    int off = atomicAdd(&lhist[b], 1);
                    int idx = lbase[b] + off;
                    if (idx < CAP) {
                        ushort4 rec;
                        rec.x = (unsigned short)((lr1 << 7) | lc1);
                        rec.y = (unsigned short)(rb[it] & 0xffffu);
                        rec.z = (unsigned short)(rb[it] >> 16);
                        rec.w = (unsigned short)rc[it];
                        bins[(size_t)b * CAP + idx] = rec;
                    }
                }
        }
    }
}

// ---------------------------------------------------------------------------
// pass 2 (fused): one block per 32x64 output tile (cols ox0=32*btx, rows
// oy0=64*bty). Patch = canvas rows [64*bty, +96) x cols [32*btx, +64), LDS
// 96x65 floats = 25.0 KB -> 6 blocks/CU; 256 threads. Splat from 2 row-buckets
// x (1 or 2) col-buckets with exact dedup (skip lr1==0 in lower row-bucket,
// skip lc1==0 in right col-bucket; range tests drop the rest). hconv written
// back into patch cols 0..31; vconv + coalesced store. Conflict-free maps:
// hconv lanes walk consecutive rows (bank = row mod 32), vconv lanes walk
// consecutive cols. __launch_bounds__(256,4): VGPR cap 128 (R12: cap 32 ->
// 100 MB spill; never raise the min-waves arg).
// ---------------------------------------------------------------------------
__global__ __launch_bounds__(256, 4) void fused_kernel(const ushort4* __restrict__ bins,
                                                       const int* __restrict__ cursor,
                                                       float* __restrict__ out) {
    __shared__ float patch[96 * PST];   // 25.0 KB
    const int tid = threadIdx.x;
    const int btx = blockIdx.x;         // 0..63  (32-col tiles)
    const int bty = blockIdx.y;         // 0..31  (64-row tiles)
    float wreg[RAD + 1];
    make_weights(wreg);

    for (int i = tid; i < 96 * PST; i += 256) patch[i] = 0.0f;
    __syncthreads();

    // --- splat ---
    const int odd = btx & 1;
    for (int dr = 0; dr <= 1; ++dr) {
        for (int cbi = 0; cbi <= odd; ++cbi) {
            const int cb   = (btx >> 1) + cbi;
            const int dcol = odd ? (cbi ? 32 : -32) : 0;
            const int bkt  = (bty + dr) * TDIM + cb;
            const int cnt  = min(cursor[bkt * CSTR], CAP);
            const ushort4* bp = bins + (size_t)bkt * CAP;
            for (int i = tid; i < cnt; i += 256) {
                ushort4 r = bp[i];
                int lr1 = r.x >> 7, lc1 = r.x & 127;     // 0..64
                if (dr && (lr1 == 0 || lr1 > 32)) continue;      // row dedup + range
                if (dcol == 32 && lc1 == 0) continue;            // col dedup
                int p0 = (dr << 6) + lr1 - 1;            // [-1, 95]
                int c0 = dcol + lc1 - 1;
                if (c0 < -1 || c0 > 63) continue;        // col range
                float dx = __half2float(__ushort_as_half(r.y));
                float dy = __half2float(__ushort_as_half(r.z));
                float I  = __half2float(__ushort_as_half(r.w));
                float wy0 = (1.0f - dy) * I, wy1 = dy * I;
                float wx0 = 1.0f - dx,      wx1 = dx;
                bool ca = (c0 >= 0), cb2 = (c0 <= 62);
                if (p0 >= 0) {
                    if (ca)  atomicAdd(&patch[p0 * PST + c0],     wy0 * wx0);
                    if (cb2) atomicAdd(&patch[p0 * PST + c0 + 1], wy0 * wx1);
                }
                if (p0 <= 94) {
                    if (ca)  atomicAdd(&patch[(p0 + 1) * PST + c0],     wy1 * wx0);
                    if (cb2) atomicAdd(&patch[(p0 + 1) * PST + c0 + 1], wy1 * wx1);
                }
            }
        }
    }
    __syncthreads();

    // --- hconv: 384 tasks (96 rows x 4 col-groups of 8), row-major -> lanes
    // hit consecutive rows (conflict-free). Into registers, then write back.
    const int rowA = tid % 96,         gA = tid / 96;          // tasks 0..255
    const int rowB = (tid + 256) % 96, gB = (tid + 256) / 96;  // tasks 256..383
    float aA[8], aB[8];
    conv8(&patch[rowA * PST + gA * 8], 1, wreg, aA);
    if (tid < 128) conv8(&patch[rowB * PST + gB * 8], 1, wreg, aB);
    __syncthreads();
#pragma unroll
    for (int k = 0; k < 8; ++k) patch[rowA * PST + gA * 8 + k] = aA[k];
    if (tid < 128) {
#pragma unroll
        for (int k = 0; k < 8; ++k) patch[rowB * PST + gB * 8 + k] = aB[k];
    }
    __syncthreads();

    // --- vconv + store: 256 tasks (8 row-groups x 32 cols), lanes on cols ---
    const int c  = tid & 31;
    const int rg = tid >> 5;           // 0..7
    float a[8];
    conv8(&patch[(rg << 3) * PST + c], PST, wreg, a);
    const int oy0 = bty << 6, ox0 = btx << 5;
#pragma unroll
    for (int k = 0; k < 8; ++k)
        out[(size_t)(oy0 + (rg << 3) + k) * WOUT + ox0 + c] = a[k];
}

extern "C" void kernel_launch(void* const* d_in, const int* in_sizes, int n_in,
                              void* d_out, int out_size, void* d_ws, size_t ws_size,
                              hipStream_t stream) {
    const float2* pos   = (const float2*)d_in[0];   // (N,2) as (x,y)
    const float*  inten = (const float*)d_in[1];
    int n = in_sizes[1];

    ushort4* bins   = (ushort4*)d_ws;                             // NT*CAP*8 = 13.4 MB
    int*     cursor = (int*)((char*)d_ws + (size_t)NT * CAP * 8); // NT*CSTR ints

    hipMemsetAsync(cursor, 0, (size_t)NT * CSTR * sizeof(int), stream);  // 69.7 KB
    scatter_kernel<<<NBLK, SCAT_T, 0, stream>>>(pos, inten, cursor, bins, n);
    fused_kernel<<<dim3(64, 32), 256, 0, stream>>>(bins, cursor, (float*)d_out);
}